// Round 1
// baseline (167.009 us; speedup 1.0000x reference)
//
#include <hip/hip_runtime.h>

// Problem constants
static constexpr int IN_C   = 32;   // in caps
static constexpr int IC_SZ  = 8;    // in cap size
static constexpr int ON_C   = 32;   // out caps
static constexpr int OC_SZ  = 16;   // out cap size
static constexpr int KKI    = 288;  // 3*3*IN_C routes
static constexpr int BATCH  = 4;
static constexpr int IH     = 14, IW = 14;
static constexpr int OHW    = 12;             // output spatial
static constexpr int NSP    = 144;            // OHW*OHW
static constexpr int NTOT   = BATCH * NSP;    // 576
static constexpr int TKLEN  = KKI * IC_SZ;    // 2304 floats per n

// ---------------------------------------------------------------------------
// K1: gather x (B, 256, 14, 14) into T[n][k][i] contiguous, n=b*144+oh*12+ow,
// k = kk*32 + ic (kk = kh*3+kw), i in [0,8). 5.3 MB in workspace.
// ---------------------------------------------------------------------------
__global__ void build_T(const float* __restrict__ x, float* __restrict__ T) {
    const int n = blockIdx.y;
    const int r = blockIdx.x * 256 + threadIdx.x;   // [0, 2304)
    const int k  = r >> 3;
    const int i  = r & 7;
    const int ic = k & 31;
    const int kk = k >> 5;
    const int kh = kk / 3, kw = kk % 3;
    const int b  = n / NSP;
    const int rm = n % NSP;
    const int oh = rm / OHW, ow = rm % OHW;
    T[n * TKLEN + r] =
        x[b * (IN_C * IC_SZ * IH * IW) + (ic * IC_SZ + i) * (IH * IW) +
          (oh + kh) * IW + (ow + kw)];
}

__device__ __forceinline__ void fma4(float4& a, float s, const float4& w) {
    a.x += s * w.x; a.y += s * w.y; a.z += s * w.z; a.w += s * w.w;
}

// ---------------------------------------------------------------------------
// K2: one block per (o, group of 4 n).  Phase 1: priors GEMM -> LDS.
// Phase 2: one wave per (o,n): dynamic routing fully in registers.
// LDS layout: P[nn][cq][k][ce]  (cq = c>>2, ce = c&3) -> float4 index
//   nn*1152 + cq*288 + k   (bank-balanced for both b128 write and read)
// ---------------------------------------------------------------------------
__global__ __launch_bounds__(256, 2)
void caps_main(const float* __restrict__ T, const float* __restrict__ Wt,
               float* __restrict__ out) {
    __shared__ float Plds[4 * 4608];   // 73.7 KB
    float4* P4 = (float4*)Plds;

    const int tid   = threadIdx.x;
    const int o     = blockIdx.y;
    const int nbase = blockIdx.x * 4;

    // ---------------- Phase 1: priors ----------------
    // thread -> c-quad cg = tid&3 (c in [4cg,4cg+4)), k-group kg = tid>>2
    {
        const int cg = tid & 3;
        const int kg = tid >> 2;            // [0,64)
        const float4* W4 = (const float4*)Wt;
        const float4* T4 = (const float4*)T;
        #pragma unroll
        for (int j = 0; j < 5; ++j) {
            const int k = kg + 64 * j;
            if (k < KKI) {
                // weight[o][k][i][4cg..4cg+3], i = 0..7
                float4 w[8];
                const int wbase = ((o * KKI + k) * 8) * 4 + cg;  // float4 units
                #pragma unroll
                for (int i = 0; i < 8; ++i) w[i] = W4[wbase + i * 4];
                #pragma unroll
                for (int nn = 0; nn < 4; ++nn) {
                    const int n = nbase + nn;
                    const float4* Tp = &T4[n * (TKLEN / 4) + k * 2];
                    const float4 t0 = Tp[0];
                    const float4 t1 = Tp[1];
                    float4 a = {0.f, 0.f, 0.f, 0.f};
                    fma4(a, t0.x, w[0]); fma4(a, t0.y, w[1]);
                    fma4(a, t0.z, w[2]); fma4(a, t0.w, w[3]);
                    fma4(a, t1.x, w[4]); fma4(a, t1.y, w[5]);
                    fma4(a, t1.z, w[6]); fma4(a, t1.w, w[7]);
                    P4[nn * 1152 + cg * 288 + k] = a;
                }
            }
        }
    }
    __syncthreads();

    // ---------------- Phase 2: routing ----------------
    const int nn   = tid >> 6;   // wave id = which n
    const int lane = tid & 63;

    // load P rows for this lane: k = 64*j + lane, j = 0..4 (j=4 valid lane<32)
    float4 p[5][4];
    #pragma unroll
    for (int j = 0; j < 5; ++j) {
        const int k = 64 * j + lane;
        const bool valid = (k < KKI);
        const int kc = valid ? k : 0;
        #pragma unroll
        for (int q = 0; q < 4; ++q) {
            float4 t = P4[nn * 1152 + q * 288 + kc];
            if (!valid) t = make_float4(0.f, 0.f, 0.f, 0.f);
            p[j][q] = t;
        }
    }

    float lj[5];
    #pragma unroll
    for (int j = 0; j < 5; ++j)
        lj[j] = (64 * j + lane < KKI) ? 0.0f : -1e30f;

    float v[16];
    #pragma unroll
    for (int it = 0; it < 3; ++it) {
        // route probabilities
        float pr[5];
        if (it == 0) {
            #pragma unroll
            for (int j = 0; j < 5; ++j)
                pr[j] = (64 * j + lane < KKI) ? (1.0f / 288.0f) : 0.0f;
        } else {
            float m = lj[0];
            #pragma unroll
            for (int j = 1; j < 5; ++j) m = fmaxf(m, lj[j]);
            #pragma unroll
            for (int sft = 1; sft < 64; sft <<= 1)
                m = fmaxf(m, __shfl_xor(m, sft));
            float S = 0.f;
            #pragma unroll
            for (int j = 0; j < 5; ++j) { pr[j] = __expf(lj[j] - m); S += pr[j]; }
            #pragma unroll
            for (int sft = 1; sft < 64; sft <<= 1)
                S += __shfl_xor(S, sft);
            const float inv = 1.0f / S;
            #pragma unroll
            for (int j = 0; j < 5; ++j) pr[j] *= inv;
        }

        // s[c] = sum_k pr[k] * P[k][c]  (in-lane partial + 64-lane butterfly)
        float sv[16];
        #pragma unroll
        for (int c = 0; c < 16; ++c) sv[c] = 0.f;
        #pragma unroll
        for (int j = 0; j < 5; ++j) {
            #pragma unroll
            for (int q = 0; q < 4; ++q) {
                sv[4 * q + 0] += pr[j] * p[j][q].x;
                sv[4 * q + 1] += pr[j] * p[j][q].y;
                sv[4 * q + 2] += pr[j] * p[j][q].z;
                sv[4 * q + 3] += pr[j] * p[j][q].w;
            }
        }
        #pragma unroll
        for (int sft = 1; sft < 64; sft <<= 1) {
            #pragma unroll
            for (int c = 0; c < 16; ++c)
                sv[c] += __shfl_xor(sv[c], sft);
        }

        // squash: v = s * sqrt(sq)/(1+sq)
        float sq = 0.f;
        #pragma unroll
        for (int c = 0; c < 16; ++c) sq += sv[c] * sv[c];
        const float scale = __fsqrt_rn(sq) / (1.0f + sq);
        #pragma unroll
        for (int c = 0; c < 16; ++c) v[c] = sv[c] * scale;

        // logits += P . v (in-lane)
        if (it < 2) {
            #pragma unroll
            for (int j = 0; j < 5; ++j) {
                float d = 0.f;
                #pragma unroll
                for (int q = 0; q < 4; ++q) {
                    d += p[j][q].x * v[4 * q + 0];
                    d += p[j][q].y * v[4 * q + 1];
                    d += p[j][q].z * v[4 * q + 2];
                    d += p[j][q].w * v[4 * q + 3];
                }
                lj[j] += d;
            }
        }
    }

    // write out: lanes 0..15 write c = lane
    if (lane < 16) {
        float ov = v[0];
        #pragma unroll
        for (int c = 1; c < 16; ++c) ov = (lane == c) ? v[c] : ov;
        const int n  = nbase + nn;
        const int b  = n / NSP;
        const int rm = n % NSP;
        const int oh = rm / OHW, ow = rm % OHW;
        out[b * (ON_C * OC_SZ * NSP) + (o * OC_SZ + lane) * NSP + oh * OHW + ow] = ov;
    }
}

extern "C" void kernel_launch(void* const* d_in, const int* in_sizes, int n_in,
                              void* d_out, int out_size, void* d_ws, size_t ws_size,
                              hipStream_t stream) {
    const float* x  = (const float*)d_in[0];   // (4, 256, 14, 14)
    const float* wt = (const float*)d_in[1];   // (32, 288, 8, 16)
    float* out = (float*)d_out;                // (4, 512, 12, 12)
    float* T   = (float*)d_ws;                 // 576*2304 floats = 5.3 MB

    build_T<<<dim3(9, NTOT), 256, 0, stream>>>(x, T);
    caps_main<<<dim3(NSP, ON_C), 256, 0, stream>>>(T, wt, out);
}

// Round 2
// 125.429 us; speedup vs baseline: 1.3315x; 1.3315x over previous
//
#include <hip/hip_runtime.h>

static constexpr int OHW = 12, NSP = 144;

// ---------------------------------------------------------------------------
// build_T: gather x (4,256,14,14) -> T[n][k][i], n = b*144+oh*12+ow,
// k = (kh*3+kw)*32 + ic, i in [0,8). One float4 (4 consecutive i) per thread.
// ---------------------------------------------------------------------------
__global__ void build_T(const float* __restrict__ x, float4* __restrict__ T4) {
    const int g = blockIdx.x * 256 + threadIdx.x;   // [0, 576*576)
    const int n = g / 576;                          // 576 float4 per n
    const int q = g - n * 576;
    const int r = q << 2;                           // float offset in row
    const int k = r >> 3;
    const int i0 = r & 7;                           // 0 or 4
    const int ic = k & 31;
    const int kk = k >> 5;
    const int kh = kk / 3, kw = kk - kh * 3;
    const int b = n / NSP;
    const int rm = n - b * NSP;
    const int oh = rm / OHW, ow = rm - oh * OHW;
    const float* xp = x + (size_t)(b * 256 + ic * 8 + i0) * 196
                        + (oh + kh) * 14 + (ow + kw);
    float4 v;
    v.x = xp[0];
    v.y = xp[196];
    v.z = xp[392];
    v.w = xp[588];
    T4[g] = v;
}

__device__ __forceinline__ void fma4(float4& a, float s, const float4& w) {
    a.x = fmaf(s, w.x, a.x);
    a.y = fmaf(s, w.y, a.y);
    a.z = fmaf(s, w.z, a.z);
    a.w = fmaf(s, w.w, a.w);
}

__device__ __forceinline__ float4 shfl_xor4(const float4& v, int m) {
    float4 r;
    r.x = __shfl_xor(v.x, m);
    r.y = __shfl_xor(v.y, m);
    r.z = __shfl_xor(v.z, m);
    r.w = __shfl_xor(v.w, m);
    return r;
}

// Compute one (j) group: load w[8] once, produce 4 n's prior quads, write LDS.
// LDS write address = const + lane  (lane-consecutive, conflict-free b128).
__device__ __forceinline__ void do_j(const float4* __restrict__ T4,
                                     const float4* __restrict__ W4,
                                     float4* __restrict__ Pl,
                                     int o, int nbase, int k, int cg,
                                     int g_local, int lane) {
    float4 w[8];
    const float4* wp = W4 + (size_t)(o * 288 + k) * 32 + cg;
    #pragma unroll
    for (int i = 0; i < 8; ++i) w[i] = wp[i * 4];
    #pragma unroll
    for (int nn = 0; nn < 4; ++nn) {
        const float4* tp = T4 + (size_t)(nbase + nn) * 576 + k * 2;
        const float4 t0 = tp[0];
        const float4 t1 = tp[1];
        float4 a = make_float4(0.f, 0.f, 0.f, 0.f);
        fma4(a, t0.x, w[0]); fma4(a, t0.y, w[1]);
        fma4(a, t0.z, w[2]); fma4(a, t0.w, w[3]);
        fma4(a, t1.x, w[4]); fma4(a, t1.y, w[5]);
        fma4(a, t1.z, w[6]); fma4(a, t1.w, w[7]);
        Pl[nn * 576 + g_local * 64 + lane] = a;
    }
}

// ---------------------------------------------------------------------------
// caps_main: block = (o, 4 n's). Phase 1: priors GEMM, thread = (cg, kg),
// 4-n weight amortization in registers. Handoff: two 9-slab LDS chunks,
// layout [nn][g][kgp][cg] (lane-consecutive both sides). Phase 2: wave = one
// n, lane = (cg, kgp), k = kgp + 16*jj; routing fully intra-wave:
// k-reduce = shfl_xor {4,8,16,32}, c-reduce = shfl_xor {1,2}. 3 barriers total.
// ---------------------------------------------------------------------------
__global__ __launch_bounds__(256, 4)
void caps_main(const float4* __restrict__ T4, const float4* __restrict__ W4,
               float* __restrict__ out) {
    __shared__ float4 Pl[4 * 9 * 64];   // 36,864 B -> 4 blocks/CU
    const int tid = threadIdx.x;
    const int o = blockIdx.y;
    const int nbase = blockIdx.x * 4;
    const int cg = tid & 3;
    const int kg = tid >> 2;     // [0,64)
    const int wv = tid >> 6;
    const int lane = tid & 63;

    float4 P[18];

    // ---- phase 1, chunk 0: g = wv + 4j in [0,9) ----
    #pragma unroll
    for (int j = 0; j < 5; ++j) {
        const int k = kg + 64 * j;
        const int g = wv + 4 * j;
        if (k < 288 && g < 9)
            do_j(T4, W4, Pl, o, nbase, k, cg, g, lane);
    }
    __syncthreads();
    #pragma unroll
    for (int jj = 0; jj < 9; ++jj)
        P[jj] = Pl[wv * 576 + jj * 64 + lane];
    __syncthreads();
    // ---- phase 1, chunk 1: g in [9,18) ----
    #pragma unroll
    for (int j = 0; j < 5; ++j) {
        const int k = kg + 64 * j;
        const int g = wv + 4 * j;
        if (k < 288 && g >= 9)
            do_j(T4, W4, Pl, o, nbase, k, cg, g - 9, lane);
    }
    __syncthreads();
    #pragma unroll
    for (int jj = 9; jj < 18; ++jj)
        P[jj] = Pl[wv * 576 + (jj - 9) * 64 + lane];

    // ---- phase 2: dynamic routing, wave = n (= nbase + wv) ----
    float lj[18];
    #pragma unroll
    for (int jj = 0; jj < 18; ++jj) lj[jj] = 0.f;
    float4 vq = make_float4(0.f, 0.f, 0.f, 0.f);

    #pragma unroll
    for (int it = 0; it < 3; ++it) {
        float4 svU = make_float4(0.f, 0.f, 0.f, 0.f);
        float S;
        if (it == 0) {
            #pragma unroll
            for (int jj = 0; jj < 18; ++jj) {
                svU.x += P[jj].x; svU.y += P[jj].y;
                svU.z += P[jj].z; svU.w += P[jj].w;
            }
            #pragma unroll
            for (int m = 4; m < 64; m <<= 1) {
                const float4 t = shfl_xor4(svU, m);
                svU.x += t.x; svU.y += t.y; svU.z += t.z; svU.w += t.w;
            }
            S = 288.0f;
        } else {
            S = 0.f;
            #pragma unroll
            for (int jj = 0; jj < 18; ++jj) {
                const float e = __expf(lj[jj]);   // |lj| small; no max needed
                S += e;
                fma4(svU, e, P[jj]);
            }
            #pragma unroll
            for (int m = 4; m < 64; m <<= 1) {
                const float4 t = shfl_xor4(svU, m);
                svU.x += t.x; svU.y += t.y; svU.z += t.z; svU.w += t.w;
                S += __shfl_xor(S, m);
            }
        }
        const float invS = __frcp_rn(S);
        float4 s;
        s.x = svU.x * invS; s.y = svU.y * invS;
        s.z = svU.z * invS; s.w = svU.w * invS;
        float sq = s.x * s.x + s.y * s.y + s.z * s.z + s.w * s.w;
        sq += __shfl_xor(sq, 1);
        sq += __shfl_xor(sq, 2);
        const float scale = __fsqrt_rn(sq) / (1.0f + sq);
        vq.x = s.x * scale; vq.y = s.y * scale;
        vq.z = s.z * scale; vq.w = s.w * scale;

        if (it < 2) {
            #pragma unroll
            for (int jj = 0; jj < 18; ++jj) {
                float d = P[jj].x * vq.x + P[jj].y * vq.y +
                          P[jj].z * vq.z + P[jj].w * vq.w;
                d += __shfl_xor(d, 1);
                d += __shfl_xor(d, 2);
                lj[jj] += d;
            }
        }
    }

    // ---- store: lanes kgp==0 write their c-quad ----
    if ((lane >> 2) == 0) {
        const int n = nbase + wv;
        const int b = n / NSP;
        const int rm = n - b * NSP;
        float* op = out + (size_t)(b * 512 + o * 16 + cg * 4) * NSP + rm;
        op[0 * NSP] = vq.x;
        op[1 * NSP] = vq.y;
        op[2 * NSP] = vq.z;
        op[3 * NSP] = vq.w;
    }
}

extern "C" void kernel_launch(void* const* d_in, const int* in_sizes, int n_in,
                              void* d_out, int out_size, void* d_ws, size_t ws_size,
                              hipStream_t stream) {
    const float* x  = (const float*)d_in[0];   // (4, 256, 14, 14)
    const float* wt = (const float*)d_in[1];   // (32, 288, 8, 16)
    float* out = (float*)d_out;                // (4, 512, 12, 12)
    float4* T4 = (float4*)d_ws;                // 576*2304 floats = 5.3 MB

    build_T<<<dim3(576 * 576 / 256), 256, 0, stream>>>(x, T4);
    caps_main<<<dim3(144, 32), 256, 0, stream>>>(T4, (const float4*)wt, out);
}